// Round 21
// baseline (116.918 us; speedup 1.0000x reference)
//
#include <hip/hip_runtime.h>

typedef unsigned short u16;
typedef __bf16 bf16_t;
typedef bf16_t bf16x8 __attribute__((ext_vector_type(8)));
typedef float f32x4 __attribute__((ext_vector_type(4)));
typedef u16 u16x8 __attribute__((ext_vector_type(8)));

__device__ __forceinline__ u16 f2bf(float f) {
  unsigned u = __float_as_uint(f);
  u += 0x7fffu + ((u >> 16) & 1u);
  return (u16)(u >> 16);
}

__device__ __forceinline__ unsigned cvtpk(float lo, float hi) {
  unsigned r;
  asm("v_cvt_pk_bf16_f32 %0, %1, %2" : "=v"(r) : "v"(lo), "v"(hi));
  return r;
}

__device__ __forceinline__ f32x4 mfma16(bf16x8 a, bf16x8 b, f32x4 c) {
  return __builtin_amdgcn_mfma_f32_16x16x32_bf16(a, b, c, 0, 0, 0);
}

__device__ __forceinline__ void gl2lds16(const u16* g, u16* l) {
  __builtin_amdgcn_global_load_lds(
      (__attribute__((address_space(1))) void*)(u16*)g,
      (__attribute__((address_space(3))) void*)l, 16, 0, 0);
}

__device__ __forceinline__ void cast8(const float* __restrict__ in,
                                      u16* __restrict__ out, int i) {
  float4 a = *(const float4*)&in[i];
  float4 b = *(const float4*)&in[i + 4];
  uint4 o;
  o.x = cvtpk(a.x, a.y);
  o.y = cvtpk(a.z, a.w);
  o.z = cvtpk(b.x, b.y);
  o.w = cvtpk(b.z, b.w);
  *(uint4*)&out[i] = o;
}

// -------- megacast: weight f32->bf16 casts + trig table (x-cast removed) ----
__global__ __launch_bounds__(256) void megacast(
    const float* __restrict__ Wq, const float* __restrict__ Wk,
    const float* __restrict__ Wv, const float* __restrict__ Wp,
    u16* __restrict__ wallb, u16* __restrict__ wpb, float2* __restrict__ tbl) {
  const int blk = blockIdx.x;
  const int tid = threadIdx.x;
  if (blk < 512) {
    cast8(Wq, wallb, (blk * 256 + tid) * 8);
  } else if (blk < 640) {
    cast8(Wk, wallb + 1048576, ((blk - 512) * 256 + tid) * 8);
  } else if (blk < 768) {
    cast8(Wv, wallb + 1310720, ((blk - 640) * 256 + tid) * 8);
  } else if (blk < 1280) {
    cast8(Wp, wpb, ((blk - 768) * 256 + tid) * 8);
  } else {
    const int idx = (blk - 1280) * 256 + tid;  // < 65536
    const int s = idx >> 5, i = idx & 31;
    float inv = exp2f(-(float)i * (13.287712379549449f / 32.0f));
    float fr = (float)s * inv;
    float sn, cs;
    sincosf(fr, &sn, &cs);
    tbl[idx] = make_float2(cs, sn);
  }
}

// ---------------- proj GEMM: 1D grid + XCD-chunked swizzle (R19 exact) ------
template <int BM, int BN, int NTN, bool O16>
__global__ __launch_bounds__(256) void gemm_bt(const u16* __restrict__ A,
                                               const u16* __restrict__ B,
                                               void* __restrict__ Cv,
                                               int M, int N, int K) {
  constexpr int FM = BM / 32;
  constexpr int FN = BN / 32;
  constexpr int NL = (BM + BN) / 32;
  __shared__ __align__(16) u16 As[2][BM][64];
  __shared__ __align__(16) u16 Bs[2][BN][64];
  const int tid = threadIdx.x;
  const int lane = tid & 63;
  const int lg = lane >> 4, li = lane & 15;
  const int wave = tid >> 6;
  const int wr = (wave >> 1) * (BM / 2), wc = (wave & 1) * (BN / 2);
  const int wid = (blockIdx.x & 7) * (gridDim.x >> 3) + (blockIdx.x >> 3);
  const int m0 = (wid / NTN) * BM, n0 = (wid % NTN) * BN;

  const int s_r = tid >> 3;
  const int s_c = (tid & 7) ^ ((tid >> 3) & 7);
  const int rdsw = li & 7;

  auto GSTAGE = [&](int buf, int k0) {
    const u16* ga = &A[(size_t)(m0 + s_r) * K + k0 + s_c * 8];
#pragma unroll
    for (int i = 0; i < BM / 32; i++)
      gl2lds16(ga + (size_t)(i * 32) * K, &As[buf][i * 32][0] + (size_t)tid * 8);
    const u16* gb = &B[(size_t)(n0 + s_r) * K + k0 + s_c * 8];
#pragma unroll
    for (int i = 0; i < BN / 32; i++)
      gl2lds16(gb + (size_t)(i * 32) * K, &Bs[buf][i * 32][0] + (size_t)tid * 8);
  };

  const f32x4 fz = {0.f, 0.f, 0.f, 0.f};
  f32x4 acc[FM][FN];
#pragma unroll
  for (int i = 0; i < FM; i++)
#pragma unroll
    for (int j = 0; j < FN; j++) acc[i][j] = fz;

  GSTAGE(0, 0);
  int buf = 0;
  const int nk = K >> 6;
  for (int t = 0; t < nk; ++t) {
    if (t + 1 < nk) {
      GSTAGE(buf ^ 1, (t + 1) * 64);
      if constexpr (NL == 6)
        asm volatile("s_waitcnt vmcnt(6)" ::: "memory");
      else
        asm volatile("s_waitcnt vmcnt(8)" ::: "memory");
    } else {
      asm volatile("s_waitcnt vmcnt(0)" ::: "memory");
    }
    __builtin_amdgcn_s_barrier();
#pragma unroll
    for (int kk = 0; kk < 2; kk++) {
      bf16x8 af[FM], bfr[FN];
#pragma unroll
      for (int i = 0; i < FM; i++)
        af[i] = *(const bf16x8*)&As[buf][wr + i * 16 + li]
                                   [((kk * 4 + lg) ^ rdsw) * 8];
#pragma unroll
      for (int j = 0; j < FN; j++)
        bfr[j] = *(const bf16x8*)&Bs[buf][wc + j * 16 + li]
                                    [((kk * 4 + lg) ^ rdsw) * 8];
      __builtin_amdgcn_s_setprio(1);
#pragma unroll
      for (int i = 0; i < FM; i++)
#pragma unroll
        for (int j = 0; j < FN; j++) acc[i][j] = mfma16(af[i], bfr[j], acc[i][j]);
      __builtin_amdgcn_s_setprio(0);
    }
    __builtin_amdgcn_s_barrier();
    buf ^= 1;
  }
#pragma unroll
  for (int i = 0; i < FM; i++)
#pragma unroll
    for (int j = 0; j < FN; j++)
#pragma unroll
      for (int r = 0; r < 4; r++) {
        const size_t idx =
            (size_t)(m0 + wr + i * 16 + lg * 4 + r) * N + n0 + wc + j * 16 + li;
        if constexpr (O16)
          ((u16*)Cv)[idx] = f2bf(acc[i][j][r]);
        else
          ((float*)Cv)[idx] = acc[i][j][r];
      }
}

// ------ QKV GEMM reading x as f32 (A reg-staged+cast) + fused epilogue ------
__global__ __launch_bounds__(256) void gemm_qkv(const float* __restrict__ X,
                                                const u16* __restrict__ Bw,
                                                const float* __restrict__ qg,
                                                u16* __restrict__ qhb,
                                                u16* __restrict__ khb,
                                                u16* __restrict__ vtb,
                                                const float2* __restrict__ tbl) {
  const int K = 1024, S = 2048;
  // LDS pool: staging = As 16 KB + Bs(2) 16 KB; epilogue = acc_t 32 KB + sw 1 KB
  __shared__ __align__(16) u16 pool[17536];  // 34.25 KB
  u16* Asl = pool;                       // [128][64]
  u16* Bsl = pool + 8192;                // [2][64][64]
  const int tid = threadIdx.x;
  const int lane = tid & 63;
  const int lg = lane >> 4, li = lane & 15;
  const int wave = tid >> 6;
  const int wr = (wave >> 1) * 64, wc = (wave & 1) * 32;
  const int wid = (blockIdx.x & 7) * 96 + (blockIdx.x >> 3);
  const int mt = wid / 24;
  const int ntile = wid - mt * 24;
  const int m0 = mt * 128;

  const int s_r = tid >> 3;
  const int s_c = (tid & 7) ^ ((tid >> 3) & 7);
  const int rdsw = li & 7;

  const float* ga = X + (size_t)(m0 + s_r) * K + s_c * 8;
  const u16* gb0 = Bw + (size_t)(ntile * 64 + s_r) * K + s_c * 8;

#define LOADA(dst, k0)                                                        \
  {                                                                           \
    _Pragma("unroll") for (int i = 0; i < 4; i++) {                           \
      dst[2 * i] = *(const float4*)(ga + (size_t)(i * 32) * K + (k0));        \
      dst[2 * i + 1] =                                                        \
          *(const float4*)(ga + (size_t)(i * 32) * K + (k0) + 4);             \
    }                                                                         \
  }
#define STAGEB(buf, k0)                                                       \
  {                                                                           \
    gl2lds16(gb0 + (k0), Bsl + (size_t)(buf)*4096 + (size_t)tid * 8);         \
    gl2lds16(gb0 + (size_t)32 * K + (k0),                                     \
             Bsl + (size_t)(buf)*4096 + 32 * 64 + (size_t)tid * 8);           \
  }
#define WRITEA(src)                                                           \
  {                                                                           \
    _Pragma("unroll") for (int i = 0; i < 4; i++) {                           \
      uint4 w;                                                                \
      w.x = cvtpk(src[2 * i].x, src[2 * i].y);                                \
      w.y = cvtpk(src[2 * i].z, src[2 * i].w);                                \
      w.z = cvtpk(src[2 * i + 1].x, src[2 * i + 1].y);                        \
      w.w = cvtpk(src[2 * i + 1].z, src[2 * i + 1].w);                        \
      *(uint4*)(Asl + (size_t)(i * 32) * 64 + (size_t)tid * 8) = w;           \
    }                                                                         \
  }

  const f32x4 fz = {0.f, 0.f, 0.f, 0.f};
  f32x4 acc[4][2];
#pragma unroll
  for (int i = 0; i < 4; i++)
#pragma unroll
    for (int j = 0; j < 2; j++) acc[i][j] = fz;

  float4 aA[8], aB[8];
  LOADA(aA, 0)
  STAGEB(0, 0)
  int buf = 0;

#define QKV_BODY(t, CUR, NXT)                                                 \
  {                                                                           \
    if ((t) + 1 < 16) {                                                       \
      LOADA(NXT, ((t) + 1) * 64)                                              \
      STAGEB(buf ^ 1, ((t) + 1) * 64)                                         \
    }                                                                         \
    WRITEA(CUR)                                                               \
    if ((t) + 1 < 16)                                                         \
      asm volatile("s_waitcnt vmcnt(10) lgkmcnt(0)" ::: "memory");            \
    else                                                                      \
      asm volatile("s_waitcnt vmcnt(0) lgkmcnt(0)" ::: "memory");             \
    __builtin_amdgcn_s_barrier();                                             \
    _Pragma("unroll") for (int kk = 0; kk < 2; kk++) {                        \
      bf16x8 af[4], bfr[2];                                                   \
      _Pragma("unroll") for (int i = 0; i < 4; i++) af[i] =                   \
          *(const bf16x8*)(Asl + (size_t)(wr + i * 16 + li) * 64 +            \
                           ((kk * 4 + lg) ^ rdsw) * 8);                       \
      _Pragma("unroll") for (int j = 0; j < 2; j++) bfr[j] =                  \
          *(const bf16x8*)(Bsl + (size_t)buf * 4096 +                         \
                           (size_t)(wc + j * 16 + li) * 64 +                  \
                           ((kk * 4 + lg) ^ rdsw) * 8);                       \
      __builtin_amdgcn_s_setprio(1);                                          \
      _Pragma("unroll") for (int i = 0; i < 4; i++)                           \
          _Pragma("unroll") for (int j = 0; j < 2; j++) acc[i][j] =           \
              mfma16(af[i], bfr[j], acc[i][j]);                               \
      __builtin_amdgcn_s_setprio(0);                                          \
    }                                                                         \
    __builtin_amdgcn_s_barrier();                                             \
    buf ^= 1;                                                                 \
  }

  for (int t = 0; t < 16; t += 2) {
    QKV_BODY(t, aA, aB)
    QKV_BODY(t + 1, aB, aA)
  }
#undef QKV_BODY
#undef LOADA
#undef STAGEB
#undef WRITEA

  // ---- fused epilogue (all waves past final barrier; LDS pool reusable) ----
  if (ntile < 20) {
    float* acc_t = (float*)pool;           // [4][64][32] f32 = 32 KB
    float* sw = (float*)(pool + 16384);    // [4][64] f32 = 1 KB
    float ssq[4][4];
#pragma unroll
    for (int i = 0; i < 4; i++)
#pragma unroll
      for (int r = 0; r < 4; r++) {
        float s2 = acc[i][0][r] * acc[i][0][r] + acc[i][1][r] * acc[i][1][r];
        s2 += __shfl_xor(s2, 1);
        s2 += __shfl_xor(s2, 2);
        s2 += __shfl_xor(s2, 4);
        s2 += __shfl_xor(s2, 8);
        ssq[i][r] = s2;
        const int rowidx = i * 16 + lg * 4 + r;
        if (li == 0) sw[wave * 64 + rowidx] = s2;
#pragma unroll
        for (int j = 0; j < 2; j++)
          acc_t[wave * 2048 + rowidx * 32 + j * 16 + li] = acc[i][j][r];
      }
    __syncthreads();
    const int pw = wave ^ 1;
    const float qsc =
        (ntile < 16) ? 0.18033688011112042f * qg[ntile] : 1.0f;
#pragma unroll
    for (int i = 0; i < 4; i++)
#pragma unroll
      for (int r = 0; r < 4; r++) {
        const int rowidx = i * 16 + lg * 4 + r;
        const float stot = ssq[i][r] + sw[pw * 64 + rowidx];
        const float rn = rsqrtf(stot * (1.0f / 64.0f) + 1.1920929e-07f);
        const int grow = m0 + wr + rowidx;
        const int srow = grow & 2047;
        const int bb = grow >> 11;
#pragma unroll
        for (int j = 0; j < 2; j++) {
          const int fi = j * 16 + li;
          const float2 cs2 = tbl[srow * 32 + fi];
          const float vn = acc[i][j][r] * rn;
          const float pvn = acc_t[pw * 2048 + rowidx * 32 + fi] * rn;
          float o = (wc == 0) ? (vn * cs2.x + pvn * cs2.y)
                              : (vn * cs2.x - pvn * cs2.y);
          o *= qsc;
          const int col = wc + fi;
          if (ntile < 16)
            qhb[((size_t)(bb * 16 + ntile) * S + srow) * 64 + col] = f2bf(o);
          else
            khb[((size_t)(bb * 4 + (ntile - 16)) * S + srow) * 64 + col] =
                f2bf(o);
        }
      }
  } else {
    u16* T = pool;  // [128][67] u16
#pragma unroll
    for (int i = 0; i < 4; i++)
#pragma unroll
      for (int j = 0; j < 2; j++)
#pragma unroll
        for (int r = 0; r < 4; r++)
          T[(wr + i * 16 + lg * 4 + r) * 67 + wc + j * 16 + li] =
              f2bf(acc[i][j][r]);
    __syncthreads();
    const int kv = ntile - 20;
    const int d = tid >> 2;
    const int sq = (tid & 3) * 32;
    const int bb = m0 >> 11;
    const int s0 = (m0 & 2047) + sq;
    unsigned* dst = (unsigned*)(vtb + ((size_t)(bb * 4 + kv) * 64 + d) * S + s0);
#pragma unroll
    for (int k2 = 0; k2 < 16; k2++) {
      unsigned lo = T[(sq + 2 * k2) * 67 + d];
      unsigned hi = T[(sq + 2 * k2 + 1) * 67 + d];
      dst[k2] = lo | (hi << 16);
    }
  }
}

// ---------------- flash attention v13 (in-register P, known-best) -----------
__global__ __launch_bounds__(256) void attn13(const u16* __restrict__ qh,
                                              const u16* __restrict__ kh,
                                              const u16* __restrict__ vt,
                                              const float* __restrict__ qg,
                                              u16* __restrict__ y, int S) {
  const int bh = blockIdx.x & 31;
  const int g = blockIdx.x >> 5;
  const int d = g & 7, u = g >> 3;
  const int qb = (u == 0) ? 31 - d : (u == 1) ? 16 + d : (u == 2) ? 15 - d : d;
  const int h = bh & 15, b = bh >> 4;
  const int kvh = h >> 2;
  const int tid = threadIdx.x;
  const int wave = tid >> 6;
  const int lane = tid & 63;
  const int lg = lane >> 4, li = lane & 15;
  const int q0 = qb * 64 + wave * 16;
  const int qrow = q0 + li;
  const float mrow = 11.541560327111707f * fabsf(qg[h]);

  const u16* qp = qh + ((size_t)(b * 16 + h) * S + q0) * 64;
  const u16* kp = kh + (size_t)(b * 4 + kvh) * S * 64;
  const u16* vp = vt + (size_t)(b * 4 + kvh) * 64 * S;

  __shared__ __align__(16) u16 Ks[2][64][64];
  __shared__ __align__(16) u16 Vs[2][64][64];

  const int s_r0 = tid >> 3;
  const int s_rp = (s_r0 & ~24) | ((s_r0 & 8) << 1) | ((s_r0 & 16) >> 1);
  const int s_c = (tid & 7) ^ ((tid >> 3) & 7);
  const int rdsw = li & 7;
  const f32x4 minit = {-mrow, -mrow, -mrow, -mrow};
  const f32x4 fz = {0.f, 0.f, 0.f, 0.f};
  const u16x8 ones_u = {0x3F80, 0x3F80, 0x3F80, 0x3F80,
                        0x3F80, 0x3F80, 0x3F80, 0x3F80};
  const bf16x8 onesb = *(const bf16x8*)&ones_u;

#define STAGE(buf, kb)                                                        \
  {                                                                           \
    const u16* gk = kp + (size_t)((kb) + s_rp) * 64 + s_c * 8;                \
    gl2lds16(gk, &Ks[buf][0][0] + (size_t)tid * 8);                           \
    gl2lds16(gk + (size_t)32 * 64, &Ks[buf][32][0] + (size_t)tid * 8);        \
    const u16* gv = vp + (size_t)s_r0 * S + (kb) + s_c * 8;                   \
    gl2lds16(gv, &Vs[buf][0][0] + (size_t)tid * 8);                           \
    gl2lds16(gv + (size_t)32 * S, &Vs[buf][32][0] + (size_t)tid * 8);         \
  }

  STAGE(0, 0)
  const bf16x8 qf0 = *(const bf16x8*)&qp[li * 64 + lg * 8];
  const bf16x8 qf1 = *(const bf16x8*)&qp[li * 64 + 32 + lg * 8];

  f32x4 o[4];
#pragma unroll
  for (int j = 0; j < 4; j++) o[j] = fz;
  f32x4 lsum = fz;

  int buf = 0;
  for (int tt = 0; tt <= qb; ++tt) {
    if (tt < qb) {
      STAGE(buf ^ 1, (tt + 1) * 64)
      asm volatile("s_waitcnt vmcnt(4)" ::: "memory");
    } else {
      asm volatile("s_waitcnt vmcnt(0)" ::: "memory");
    }
    __builtin_amdgcn_s_barrier();
    const int kb = tt * 64;
    f32x4 s[4];
    __builtin_amdgcn_s_setprio(1);
#pragma unroll
    for (int t = 0; t < 4; t++) {
      const bf16x8 ka =
          *(const bf16x8*)&Ks[buf][t * 16 + li][((lg) ^ rdsw) * 8];
      const bf16x8 kc =
          *(const bf16x8*)&Ks[buf][t * 16 + li][((lg + 4) ^ rdsw) * 8];
      s[t] = mfma16(ka, qf0, minit);
      s[t] = mfma16(kc, qf1, s[t]);
    }
    __builtin_amdgcn_s_setprio(0);
    float pv[16];
    if (tt < qb) {
#pragma unroll
      for (int t = 0; t < 4; t++)
#pragma unroll
        for (int r = 0; r < 4; r++) pv[t * 4 + r] = exp2f(s[t][r]);
    } else {
#pragma unroll
      for (int t = 0; t < 4; t++)
#pragma unroll
        for (int r = 0; r < 4; r++) {
          const int key = kb + ((t >> 1) << 5) + ((lg & 2) << 3) +
                          ((t & 1) << 3) + ((lg & 1) << 2) + r;
          pv[t * 4 + r] = exp2f(key > qrow ? -1e30f : s[t][r]);
        }
    }
    unsigned w0 = cvtpk(pv[0], pv[1]),   w1 = cvtpk(pv[2], pv[3]);
    unsigned w2 = cvtpk(pv[4], pv[5]),   w3 = cvtpk(pv[6], pv[7]);
    unsigned w4 = cvtpk(pv[8], pv[9]),   w5 = cvtpk(pv[10], pv[11]);
    unsigned w6 = cvtpk(pv[12], pv[13]), w7 = cvtpk(pv[14], pv[15]);
    asm("v_permlane16_swap_b32 %0, %1" : "+v"(w0), "+v"(w2));
    asm("v_permlane16_swap_b32 %0, %1" : "+v"(w1), "+v"(w3));
    asm("v_permlane16_swap_b32 %0, %1" : "+v"(w4), "+v"(w6));
    asm("v_permlane16_swap_b32 %0, %1" : "+v"(w5), "+v"(w7));
    uint4 pb0u = {w0, w1, w2, w3};
    uint4 pb1u = {w4, w5, w6, w7};
    const bf16x8 pb0 = *(const bf16x8*)&pb0u;
    const bf16x8 pb1 = *(const bf16x8*)&pb1u;
    __builtin_amdgcn_s_setprio(1);
#pragma unroll
    for (int j = 0; j < 4; j++) {
      const bf16x8 v0 =
          *(const bf16x8*)&Vs[buf][j * 16 + li][((lg) ^ rdsw) * 8];
      const bf16x8 v1 =
          *(const bf16x8*)&Vs[buf][j * 16 + li][((lg + 4) ^ rdsw) * 8];
      o[j] = mfma16(v0, pb0, o[j]);
      o[j] = mfma16(v1, pb1, o[j]);
    }
    lsum = mfma16(onesb, pb0, lsum);
    lsum = mfma16(onesb, pb1, lsum);
    __builtin_amdgcn_s_setprio(0);
    __builtin_amdgcn_s_barrier();
    buf ^= 1;
  }
#undef STAGE
  const float linv = 1.0f / lsum[0];
  u16* yp = &y[((size_t)(b * S + q0 + li)) * 1024 + h * 64];
#pragma unroll
  for (int j = 0; j < 4; j++) {
    uint2 wo;
    wo.x = cvtpk(o[j][0] * linv, o[j][1] * linv);
    wo.y = cvtpk(o[j][2] * linv, o[j][3] * linv);
    *(uint2*)(yp + j * 16 + lg * 4) = wo;
  }
}

extern "C" void kernel_launch(void* const* d_in, const int* in_sizes, int n_in,
                              void* d_out, int out_size, void* d_ws, size_t ws_size,
                              hipStream_t stream) {
  const float* x  = (const float*)d_in[0];
  const float* Wq = (const float*)d_in[1];
  const float* Wk = (const float*)d_in[2];
  const float* Wv = (const float*)d_in[3];
  const float* Wp = (const float*)d_in[4];
  const float* qg = (const float*)d_in[5];
  float* out = (float*)d_out;

  const int S = 2048;
  char* ws = (char*)d_ws;
  u16*    wallb = (u16*)(ws + 0);          // 3 MB
  u16*    wpb   = (u16*)(ws + 3145728);    // 2 MB
  float2* tbl   = (float2*)(ws + 5242880); // 512 KB
  u16*    qhb   = (u16*)(ws + 5767168);    // 8 MB
  u16*    khb   = (u16*)(ws + 14155776);   // 2 MB
  u16*    vtb   = (u16*)(ws + 16252928);   // 2 MB
  u16*    yb    = (u16*)(ws + 18350080);   // 8 MB -> 26738688
  if (ws_size < 26738688) return;

  megacast<<<1536, 256, 0, stream>>>(Wq, Wk, Wv, Wp, wallb, wpb, tbl);

  // fused QKV projection (x read as f32, A reg-cast) + RMS/RoPE/V-transpose
  gemm_qkv<<<768, 256, 0, stream>>>(x, wallb, qg, qhb, khb, vtb, tbl);

  attn13<<<1024, 256, 0, stream>>>(qhb, khb, vtb, qg, yb, S);

  // output projection: 64x128 tile, 1D grid 512 = 2/CU, XCD-chunked
  gemm_bt<64, 128, 8, false><<<512, 256, 0, stream>>>(yb, wpb, out,
                                                      4096, 1024, 1024);
}

// Round 22
// 90.244 us; speedup vs baseline: 1.2956x; 1.2956x over previous
//
#include <hip/hip_runtime.h>

typedef unsigned short u16;
typedef __bf16 bf16_t;
typedef bf16_t bf16x8 __attribute__((ext_vector_type(8)));
typedef float f32x4 __attribute__((ext_vector_type(4)));
typedef u16 u16x8 __attribute__((ext_vector_type(8)));

__device__ __forceinline__ u16 f2bf(float f) {
  unsigned u = __float_as_uint(f);
  u += 0x7fffu + ((u >> 16) & 1u);
  return (u16)(u >> 16);
}

__device__ __forceinline__ unsigned cvtpk(float lo, float hi) {
  unsigned r;
  asm("v_cvt_pk_bf16_f32 %0, %1, %2" : "=v"(r) : "v"(lo), "v"(hi));
  return r;
}

__device__ __forceinline__ f32x4 mfma16(bf16x8 a, bf16x8 b, f32x4 c) {
  return __builtin_amdgcn_mfma_f32_16x16x32_bf16(a, b, c, 0, 0, 0);
}

__device__ __forceinline__ void gl2lds16(const u16* g, u16* l) {
  __builtin_amdgcn_global_load_lds(
      (__attribute__((address_space(1))) void*)(u16*)g,
      (__attribute__((address_space(3))) void*)l, 16, 0, 0);
}

__device__ __forceinline__ void cast8(const float* __restrict__ in,
                                      u16* __restrict__ out, int i) {
  float4 a = *(const float4*)&in[i];
  float4 b = *(const float4*)&in[i + 4];
  uint4 o;
  o.x = cvtpk(a.x, a.y);
  o.y = cvtpk(a.z, a.w);
  o.z = cvtpk(b.x, b.y);
  o.w = cvtpk(b.z, b.w);
  *(uint4*)&out[i] = o;
}

// ---------------- megacast: all f32->bf16 casts + trig table ----------------
__global__ __launch_bounds__(256) void megacast(
    const float* __restrict__ x, const float* __restrict__ Wq,
    const float* __restrict__ Wk, const float* __restrict__ Wv,
    const float* __restrict__ Wp, u16* __restrict__ xb,
    u16* __restrict__ wallb, u16* __restrict__ wpb,
    float2* __restrict__ tbl) {
  const int blk = blockIdx.x;
  const int tid = threadIdx.x;
  if (blk < 2048) {
    cast8(x, xb, (blk * 256 + tid) * 8);
  } else if (blk < 2560) {
    cast8(Wq, wallb, ((blk - 2048) * 256 + tid) * 8);
  } else if (blk < 2688) {
    cast8(Wk, wallb + 1048576, ((blk - 2560) * 256 + tid) * 8);
  } else if (blk < 2816) {
    cast8(Wv, wallb + 1310720, ((blk - 2688) * 256 + tid) * 8);
  } else if (blk < 3328) {
    cast8(Wp, wpb, ((blk - 2816) * 256 + tid) * 8);
  } else {
    const int idx = (blk - 3328) * 256 + tid;  // < 65536
    const int s = idx >> 5, i = idx & 31;
    float inv = exp2f(-(float)i * (13.287712379549449f / 32.0f));
    float fr = (float)s * inv;
    float sn, cs;
    sincosf(fr, &sn, &cs);
    tbl[idx] = make_float2(cs, sn);
  }
}

// ---------------- proj GEMM: 1D grid + XCD-chunked swizzle ------------------
template <int BM, int BN, int NTN, bool O16>
__global__ __launch_bounds__(256) void gemm_bt(const u16* __restrict__ A,
                                               const u16* __restrict__ B,
                                               void* __restrict__ Cv,
                                               int M, int N, int K) {
  constexpr int FM = BM / 32;
  constexpr int FN = BN / 32;
  constexpr int NL = (BM + BN) / 32;
  __shared__ __align__(16) u16 As[2][BM][64];
  __shared__ __align__(16) u16 Bs[2][BN][64];
  const int tid = threadIdx.x;
  const int lane = tid & 63;
  const int lg = lane >> 4, li = lane & 15;
  const int wave = tid >> 6;
  const int wr = (wave >> 1) * (BM / 2), wc = (wave & 1) * (BN / 2);
  const int wid = (blockIdx.x & 7) * (gridDim.x >> 3) + (blockIdx.x >> 3);
  const int m0 = (wid / NTN) * BM, n0 = (wid % NTN) * BN;

  const int s_r = tid >> 3;
  const int s_c = (tid & 7) ^ ((tid >> 3) & 7);
  const int rdsw = li & 7;

  auto GSTAGE = [&](int buf, int k0) {
    const u16* ga = &A[(size_t)(m0 + s_r) * K + k0 + s_c * 8];
#pragma unroll
    for (int i = 0; i < BM / 32; i++)
      gl2lds16(ga + (size_t)(i * 32) * K, &As[buf][i * 32][0] + (size_t)tid * 8);
    const u16* gb = &B[(size_t)(n0 + s_r) * K + k0 + s_c * 8];
#pragma unroll
    for (int i = 0; i < BN / 32; i++)
      gl2lds16(gb + (size_t)(i * 32) * K, &Bs[buf][i * 32][0] + (size_t)tid * 8);
  };

  const f32x4 fz = {0.f, 0.f, 0.f, 0.f};
  f32x4 acc[FM][FN];
#pragma unroll
  for (int i = 0; i < FM; i++)
#pragma unroll
    for (int j = 0; j < FN; j++) acc[i][j] = fz;

  GSTAGE(0, 0);
  int buf = 0;
  const int nk = K >> 6;
  for (int t = 0; t < nk; ++t) {
    if (t + 1 < nk) {
      GSTAGE(buf ^ 1, (t + 1) * 64);
      if constexpr (NL == 6)
        asm volatile("s_waitcnt vmcnt(6)" ::: "memory");
      else
        asm volatile("s_waitcnt vmcnt(8)" ::: "memory");
    } else {
      asm volatile("s_waitcnt vmcnt(0)" ::: "memory");
    }
    __builtin_amdgcn_s_barrier();
#pragma unroll
    for (int kk = 0; kk < 2; kk++) {
      bf16x8 af[FM], bfr[FN];
#pragma unroll
      for (int i = 0; i < FM; i++)
        af[i] = *(const bf16x8*)&As[buf][wr + i * 16 + li]
                                   [((kk * 4 + lg) ^ rdsw) * 8];
#pragma unroll
      for (int j = 0; j < FN; j++)
        bfr[j] = *(const bf16x8*)&Bs[buf][wc + j * 16 + li]
                                    [((kk * 4 + lg) ^ rdsw) * 8];
      __builtin_amdgcn_s_setprio(1);
#pragma unroll
      for (int i = 0; i < FM; i++)
#pragma unroll
        for (int j = 0; j < FN; j++) acc[i][j] = mfma16(af[i], bfr[j], acc[i][j]);
      __builtin_amdgcn_s_setprio(0);
    }
    __builtin_amdgcn_s_barrier();
    buf ^= 1;
  }
#pragma unroll
  for (int i = 0; i < FM; i++)
#pragma unroll
    for (int j = 0; j < FN; j++)
#pragma unroll
      for (int r = 0; r < 4; r++) {
        const size_t idx =
            (size_t)(m0 + wr + i * 16 + lg * 4 + r) * N + n0 + wc + j * 16 + li;
        if constexpr (O16)
          ((u16*)Cv)[idx] = f2bf(acc[i][j][r]);
        else
          ((float*)Cv)[idx] = acc[i][j][r];
      }
}

// ------ QKV GEMM + fused RMSNorm/RoPE/V-transpose epilogue ------------------
__global__ __launch_bounds__(256) void gemm_qkv(const u16* __restrict__ A,
                                                const u16* __restrict__ B,
                                                const float* __restrict__ qg,
                                                u16* __restrict__ qhb,
                                                u16* __restrict__ khb,
                                                u16* __restrict__ vtb,
                                                const float2* __restrict__ tbl) {
  const int K = 1024, S = 2048;
  __shared__ __align__(16) u16 As[2][128][64];   // 32 KB
  __shared__ __align__(16) u16 Bs[2][64][64];    // 16 KB
  const int tid = threadIdx.x;
  const int lane = tid & 63;
  const int lg = lane >> 4, li = lane & 15;
  const int wave = tid >> 6;
  const int wr = (wave >> 1) * 64, wc = (wave & 1) * 32;
  const int wid = (blockIdx.x & 7) * 96 + (blockIdx.x >> 3);
  const int mt = wid / 24;
  const int ntile = wid - mt * 24;
  const int m0 = mt * 128;

  const int s_r = tid >> 3;
  const int s_c = (tid & 7) ^ ((tid >> 3) & 7);
  const int rdsw = li & 7;

  auto GSTAGE = [&](int buf, int k0) {
    const u16* ga = &A[(size_t)(m0 + s_r) * K + k0 + s_c * 8];
#pragma unroll
    for (int i = 0; i < 4; i++)
      gl2lds16(ga + (size_t)(i * 32) * K, &As[buf][i * 32][0] + (size_t)tid * 8);
    const u16* gb = &B[(size_t)(ntile * 64 + s_r) * K + k0 + s_c * 8];
#pragma unroll
    for (int i = 0; i < 2; i++)
      gl2lds16(gb + (size_t)(i * 32) * K, &Bs[buf][i * 32][0] + (size_t)tid * 8);
  };

  const f32x4 fz = {0.f, 0.f, 0.f, 0.f};
  f32x4 acc[4][2];
#pragma unroll
  for (int i = 0; i < 4; i++)
#pragma unroll
    for (int j = 0; j < 2; j++) acc[i][j] = fz;

  GSTAGE(0, 0);
  int buf = 0;
  for (int t = 0; t < 16; ++t) {
    if (t + 1 < 16) {
      GSTAGE(buf ^ 1, (t + 1) * 64);
      asm volatile("s_waitcnt vmcnt(6)" ::: "memory");
    } else {
      asm volatile("s_waitcnt vmcnt(0)" ::: "memory");
    }
    __builtin_amdgcn_s_barrier();
#pragma unroll
    for (int kk = 0; kk < 2; kk++) {
      bf16x8 af[4], bfr[2];
#pragma unroll
      for (int i = 0; i < 4; i++)
        af[i] = *(const bf16x8*)&As[buf][wr + i * 16 + li]
                                   [((kk * 4 + lg) ^ rdsw) * 8];
#pragma unroll
      for (int j = 0; j < 2; j++)
        bfr[j] = *(const bf16x8*)&Bs[buf][wc + j * 16 + li]
                                    [((kk * 4 + lg) ^ rdsw) * 8];
      __builtin_amdgcn_s_setprio(1);
#pragma unroll
      for (int i = 0; i < 4; i++)
#pragma unroll
        for (int j = 0; j < 2; j++) acc[i][j] = mfma16(af[i], bfr[j], acc[i][j]);
      __builtin_amdgcn_s_setprio(0);
    }
    __builtin_amdgcn_s_barrier();
    buf ^= 1;
  }

  // ---- fused epilogue (all waves past final barrier; LDS reusable) ----
  if (ntile < 20) {
    float* acc_t = (float*)&As[0][0][0];  // [4][64][32] f32 = 32 KB
    float* sw = (float*)&Bs[0][0][0];     // [4][64] f32 = 1 KB
    float ssq[4][4];
#pragma unroll
    for (int i = 0; i < 4; i++)
#pragma unroll
      for (int r = 0; r < 4; r++) {
        float s2 = acc[i][0][r] * acc[i][0][r] + acc[i][1][r] * acc[i][1][r];
        s2 += __shfl_xor(s2, 1);
        s2 += __shfl_xor(s2, 2);
        s2 += __shfl_xor(s2, 4);
        s2 += __shfl_xor(s2, 8);
        ssq[i][r] = s2;
        const int rowidx = i * 16 + lg * 4 + r;
        if (li == 0) sw[wave * 64 + rowidx] = s2;
#pragma unroll
        for (int j = 0; j < 2; j++)
          acc_t[wave * 2048 + rowidx * 32 + j * 16 + li] = acc[i][j][r];
      }
    __syncthreads();
    const int pw = wave ^ 1;
    const float qsc =
        (ntile < 16) ? 0.18033688011112042f * qg[ntile] : 1.0f;
#pragma unroll
    for (int i = 0; i < 4; i++)
#pragma unroll
      for (int r = 0; r < 4; r++) {
        const int rowidx = i * 16 + lg * 4 + r;
        const float stot = ssq[i][r] + sw[pw * 64 + rowidx];
        const float rn = rsqrtf(stot * (1.0f / 64.0f) + 1.1920929e-07f);
        const int grow = m0 + wr + rowidx;
        const int srow = grow & 2047;
        const int bb = grow >> 11;
#pragma unroll
        for (int j = 0; j < 2; j++) {
          const int fi = j * 16 + li;
          const float2 cs2 = tbl[srow * 32 + fi];
          const float vn = acc[i][j][r] * rn;
          const float pvn = acc_t[pw * 2048 + rowidx * 32 + fi] * rn;
          float o = (wc == 0) ? (vn * cs2.x + pvn * cs2.y)
                              : (vn * cs2.x - pvn * cs2.y);
          o *= qsc;
          const int col = wc + fi;
          if (ntile < 16)
            qhb[((size_t)(bb * 16 + ntile) * S + srow) * 64 + col] = f2bf(o);
          else
            khb[((size_t)(bb * 4 + (ntile - 16)) * S + srow) * 64 + col] =
                f2bf(o);
        }
      }
  } else {
    u16* T = (u16*)&As[0][0][0];  // [128][67] u16
#pragma unroll
    for (int i = 0; i < 4; i++)
#pragma unroll
      for (int j = 0; j < 2; j++)
#pragma unroll
        for (int r = 0; r < 4; r++)
          T[(wr + i * 16 + lg * 4 + r) * 67 + wc + j * 16 + li] =
              f2bf(acc[i][j][r]);
    __syncthreads();
    const int kv = ntile - 20;
    const int d = tid >> 2;
    const int sq = (tid & 3) * 32;
    const int bb = m0 >> 11;
    const int s0 = (m0 & 2047) + sq;
    unsigned* dst = (unsigned*)(vtb + ((size_t)(bb * 4 + kv) * 64 + d) * S + s0);
#pragma unroll
    for (int k2 = 0; k2 < 16; k2++) {
      unsigned lo = T[(sq + 2 * k2) * 67 + d];
      unsigned hi = T[(sq + 2 * k2 + 1) * 67 + d];
      dst[k2] = lo | (hi << 16);
    }
  }
}

// ---------------- flash attention v13 (in-register P, known-best) -----------
__global__ __launch_bounds__(256) void attn13(const u16* __restrict__ qh,
                                              const u16* __restrict__ kh,
                                              const u16* __restrict__ vt,
                                              const float* __restrict__ qg,
                                              u16* __restrict__ y, int S) {
  const int bh = blockIdx.x & 31;
  const int g = blockIdx.x >> 5;
  const int d = g & 7, u = g >> 3;
  const int qb = (u == 0) ? 31 - d : (u == 1) ? 16 + d : (u == 2) ? 15 - d : d;
  const int h = bh & 15, b = bh >> 4;
  const int kvh = h >> 2;
  const int tid = threadIdx.x;
  const int wave = tid >> 6;
  const int lane = tid & 63;
  const int lg = lane >> 4, li = lane & 15;
  const int q0 = qb * 64 + wave * 16;
  const int qrow = q0 + li;
  const float mrow = 11.541560327111707f * fabsf(qg[h]);

  const u16* qp = qh + ((size_t)(b * 16 + h) * S + q0) * 64;
  const u16* kp = kh + (size_t)(b * 4 + kvh) * S * 64;
  const u16* vp = vt + (size_t)(b * 4 + kvh) * 64 * S;

  __shared__ __align__(16) u16 Ks[2][64][64];
  __shared__ __align__(16) u16 Vs[2][64][64];

  const int s_r0 = tid >> 3;
  const int s_rp = (s_r0 & ~24) | ((s_r0 & 8) << 1) | ((s_r0 & 16) >> 1);
  const int s_c = (tid & 7) ^ ((tid >> 3) & 7);
  const int rdsw = li & 7;
  const f32x4 minit = {-mrow, -mrow, -mrow, -mrow};
  const f32x4 fz = {0.f, 0.f, 0.f, 0.f};
  const u16x8 ones_u = {0x3F80, 0x3F80, 0x3F80, 0x3F80,
                        0x3F80, 0x3F80, 0x3F80, 0x3F80};
  const bf16x8 onesb = *(const bf16x8*)&ones_u;

#define STAGE(buf, kb)                                                        \
  {                                                                           \
    const u16* gk = kp + (size_t)((kb) + s_rp) * 64 + s_c * 8;                \
    gl2lds16(gk, &Ks[buf][0][0] + (size_t)tid * 8);                           \
    gl2lds16(gk + (size_t)32 * 64, &Ks[buf][32][0] + (size_t)tid * 8);        \
    const u16* gv = vp + (size_t)s_r0 * S + (kb) + s_c * 8;                   \
    gl2lds16(gv, &Vs[buf][0][0] + (size_t)tid * 8);                           \
    gl2lds16(gv + (size_t)32 * S, &Vs[buf][32][0] + (size_t)tid * 8);         \
  }

  STAGE(0, 0)
  const bf16x8 qf0 = *(const bf16x8*)&qp[li * 64 + lg * 8];
  const bf16x8 qf1 = *(const bf16x8*)&qp[li * 64 + 32 + lg * 8];

  f32x4 o[4];
#pragma unroll
  for (int j = 0; j < 4; j++) o[j] = fz;
  f32x4 lsum = fz;

  int buf = 0;
  for (int tt = 0; tt <= qb; ++tt) {
    if (tt < qb) {
      STAGE(buf ^ 1, (tt + 1) * 64)
      asm volatile("s_waitcnt vmcnt(4)" ::: "memory");
    } else {
      asm volatile("s_waitcnt vmcnt(0)" ::: "memory");
    }
    __builtin_amdgcn_s_barrier();
    const int kb = tt * 64;
    f32x4 s[4];
    __builtin_amdgcn_s_setprio(1);
#pragma unroll
    for (int t = 0; t < 4; t++) {
      const bf16x8 ka =
          *(const bf16x8*)&Ks[buf][t * 16 + li][((lg) ^ rdsw) * 8];
      const bf16x8 kc =
          *(const bf16x8*)&Ks[buf][t * 16 + li][((lg + 4) ^ rdsw) * 8];
      s[t] = mfma16(ka, qf0, minit);
      s[t] = mfma16(kc, qf1, s[t]);
    }
    __builtin_amdgcn_s_setprio(0);
    float pv[16];
    if (tt < qb) {
#pragma unroll
      for (int t = 0; t < 4; t++)
#pragma unroll
        for (int r = 0; r < 4; r++) pv[t * 4 + r] = exp2f(s[t][r]);
    } else {
#pragma unroll
      for (int t = 0; t < 4; t++)
#pragma unroll
        for (int r = 0; r < 4; r++) {
          const int key = kb + ((t >> 1) << 5) + ((lg & 2) << 3) +
                          ((t & 1) << 3) + ((lg & 1) << 2) + r;
          pv[t * 4 + r] = exp2f(key > qrow ? -1e30f : s[t][r]);
        }
    }
    unsigned w0 = cvtpk(pv[0], pv[1]),   w1 = cvtpk(pv[2], pv[3]);
    unsigned w2 = cvtpk(pv[4], pv[5]),   w3 = cvtpk(pv[6], pv[7]);
    unsigned w4 = cvtpk(pv[8], pv[9]),   w5 = cvtpk(pv[10], pv[11]);
    unsigned w6 = cvtpk(pv[12], pv[13]), w7 = cvtpk(pv[14], pv[15]);
    asm("v_permlane16_swap_b32 %0, %1" : "+v"(w0), "+v"(w2));
    asm("v_permlane16_swap_b32 %0, %1" : "+v"(w1), "+v"(w3));
    asm("v_permlane16_swap_b32 %0, %1" : "+v"(w4), "+v"(w6));
    asm("v_permlane16_swap_b32 %0, %1" : "+v"(w5), "+v"(w7));
    uint4 pb0u = {w0, w1, w2, w3};
    uint4 pb1u = {w4, w5, w6, w7};
    const bf16x8 pb0 = *(const bf16x8*)&pb0u;
    const bf16x8 pb1 = *(const bf16x8*)&pb1u;
    __builtin_amdgcn_s_setprio(1);
#pragma unroll
    for (int j = 0; j < 4; j++) {
      const bf16x8 v0 =
          *(const bf16x8*)&Vs[buf][j * 16 + li][((lg) ^ rdsw) * 8];
      const bf16x8 v1 =
          *(const bf16x8*)&Vs[buf][j * 16 + li][((lg + 4) ^ rdsw) * 8];
      o[j] = mfma16(v0, pb0, o[j]);
      o[j] = mfma16(v1, pb1, o[j]);
    }
    lsum = mfma16(onesb, pb0, lsum);
    lsum = mfma16(onesb, pb1, lsum);
    __builtin_amdgcn_s_setprio(0);
    __builtin_amdgcn_s_barrier();
    buf ^= 1;
  }
#undef STAGE
  const float linv = 1.0f / lsum[0];
  u16* yp = &y[((size_t)(b * S + q0 + li)) * 1024 + h * 64];
#pragma unroll
  for (int j = 0; j < 4; j++) {
    uint2 wo;
    wo.x = cvtpk(o[j][0] * linv, o[j][1] * linv);
    wo.y = cvtpk(o[j][2] * linv, o[j][3] * linv);
    *(uint2*)(yp + j * 16 + lg * 4) = wo;
  }
}

extern "C" void kernel_launch(void* const* d_in, const int* in_sizes, int n_in,
                              void* d_out, int out_size, void* d_ws, size_t ws_size,
                              hipStream_t stream) {
  const float* x  = (const float*)d_in[0];
  const float* Wq = (const float*)d_in[1];
  const float* Wk = (const float*)d_in[2];
  const float* Wv = (const float*)d_in[3];
  const float* Wp = (const float*)d_in[4];
  const float* qg = (const float*)d_in[5];
  float* out = (float*)d_out;

  const int S = 2048;
  char* ws = (char*)d_ws;
  u16*    xb    = (u16*)(ws + 0);          // 8 MB
  u16*    wallb = (u16*)(ws + 8388608);    // 3 MB
  u16*    wpb   = (u16*)(ws + 11534336);   // 2 MB
  float2* tbl   = (float2*)(ws + 13631488);// 512 KB
  u16*    qhb   = (u16*)(ws + 14155776);   // 8 MB
  u16*    khb   = (u16*)(ws + 22544384);   // 2 MB
  u16*    vtb   = (u16*)(ws + 24641536);   // 2 MB
  u16*    yb    = (u16*)(ws + 26738688);   // 8 MB -> 35127296
  if (ws_size < 35127296) return;

  megacast<<<3584, 256, 0, stream>>>(x, Wq, Wk, Wv, Wp, xb, wallb, wpb, tbl);

  // fused QKV projection + RMSNorm/RoPE/V-transpose: 768 blocks = 3/CU
  gemm_qkv<<<768, 256, 0, stream>>>(xb, wallb, qg, qhb, khb, vtb, tbl);

  attn13<<<1024, 256, 0, stream>>>(qhb, khb, vtb, qg, yb, S);

  // output projection: 64x128 tile, 1D grid 512 = 2/CU, XCD-chunked
  gemm_bt<64, 128, 8, false><<<512, 256, 0, stream>>>(yb, wpb, out,
                                                      4096, 1024, 1024);
}